// Round 7
// baseline (125.416 us; speedup 1.0000x reference)
//
#include <hip/hip_runtime.h>

// PillarVFE fused, 3 kernels + tiny memset.
//  - R7/R8: no cross-block handoff inside a kernel (fence cost).
//  - R12: raw-moment-piece accumulation; R14: pipelining NEUTRAL (compiler
//    already pipelines); R15: dedicated 1-block k2, zero-LDS k3 (130.0).
//  - R16: k3 grid-stride + k1 fat-tail REGRESSED (+6).
//  - R17 (best, 124.1): k1 compact-slot accumulation (55 replicated entries
//    distributed over octet lanes, masked-fma; tail 225 -> 101 shuffles;
//    acc VGPRs 65 -> 17; 1563 blocks x 2 tiles, 6252 co-resident waves).
//  - R18 (this round): single isolated change — k3's pt loads exec-masked to
//    half==0. Lanes 32-63 never consume pt (their A-fragment uses only rec's
//    m45), so the unmasked load wasted 25.6 MB of vf traffic (half of k3's
//    51.2 MB). R16 bundled this with the harmful grid-stride; isolating now.
// k1: 8 thr/voxel (4 pts each), coalesced; 2 tiles/block; compact register
//     accumulators; butterfly + LDS reduce + 65 unsafeAtomicAdd at block end.
//     Writes per-voxel packed record (-mean,-center bf16, cnt).
//     Slot layout: s0..3 ST_r | s4..9 ScntK_m | s10..33 K_m*T_r |
//                  s34..54 cntK_m*K_m2 | s55..64 P2 upper-tri.
// k2: one block: sum 16 acc rows (double) -> per-channel a,b (f64 chain).
// k3: A=[xyzw,-mean,-ctr]*mask in MFMA K-slots, B=a*W'' bf16, C=0 -> D=a*x;
//     out = relu(b + max_rows D). One wave = one voxel/iter, 2-deep prefetch,
//     max3 tree, pt loads masked to half==0.

typedef __attribute__((ext_vector_type(8))) short short8;     // 8 bf16
typedef __attribute__((ext_vector_type(16))) float floatx16;  // 32x32 MFMA C/D

namespace {
constexpr int V_    = 100000;
constexpr int P_    = 32;
constexpr int COUT  = 64;
constexpr int NF    = 10;
constexpr int NMOM  = 65;
constexpr int PSTRIDE = 72;
constexpr int NSETS  = 16;        // atomic accumulator rows
constexpr int NTILES = 3125;      // 32 voxels per tile
constexpr int K1_BLOCKS = 1563;   // x 2 tiles (last block: 1 tile)
constexpr int K1_TILES  = 2;
constexpr int K3_BLOCKS = 3125;   // 12500 waves x 8 iters = 100000 exactly
constexpr int K3_WAVES  = 12500;
constexpr int K3_ITERS  = 8;

constexpr float VX_ = 0.16f, VY_ = 0.16f, VZ_ = 4.0f;
constexpr float XOFF_ = 0.08f, YOFF_ = -39.60f, ZOFF_ = -1.0f;
constexpr float EPS_ = 0.001f;
}

__device__ __forceinline__ unsigned f2bfu(float x) {  // RNE -> 16-bit value
  unsigned u = __builtin_bit_cast(unsigned, x);
  u += 0x7fffu + ((u >> 16) & 1u);
  return u >> 16;
}

__device__ __forceinline__ float max3f(float a, float b, float c) {
  return fmaxf(fmaxf(a, b), c);   // fuses to v_max3_f32
}

// ---------------- Pass 1: compact raw-moment pieces ----------------
__global__ __launch_bounds__(256) void k1_stats(
    const float* __restrict__ vf, const int* __restrict__ npts,
    const int* __restrict__ coords, float* __restrict__ acc,
    int4* __restrict__ meanws)
{
  __shared__ float red[4][NMOM];

  const int tid = threadIdx.x;
  const int oct = tid & 7;          // 4-point slice within voxel
  const int vlane = tid >> 3;       // voxel-in-tile (0..31)

  // ownership masks: fm[k] = (oct==k) ? 1 : 0   (8 regs, static-indexed)
  float fm[8];
  #pragma unroll
  for (int k = 0; k < 8; ++k) fm[k] = (oct == k) ? 1.f : 0.f;

  float mc[7];                      // compact slots s = 8*j + oct, s<=54
  #pragma unroll
  for (int j = 0; j < 7; ++j) mc[j] = 0.f;
  float p2a[10];                    // per-lane P2 partials (additive)
  #pragma unroll
  for (int i = 0; i < 10; ++i) p2a[i] = 0.f;

  #pragma unroll
  for (int it = 0; it < K1_TILES; ++it) {
    const int tile = blockIdx.x * K1_TILES + it;   // 0..3125
    if (tile >= NTILES) break;                     // block-uniform guard
    const int v = tile * 32 + vlane;

    const int  cnt = npts[v];
    const int4 cd  = ((const int4*)coords)[v];

    // 4 float4 loads: 64B/thread -> wave covers 4KB contiguous
    float4 q[4];
    const float4* base = (const float4*)vf + (size_t)v * P_ + oct * 4;
    #pragma unroll
    for (int i = 0; i < 4; ++i) q[i] = base[i];

    float tx = 0.f, ty = 0.f, tz = 0.f, tw = 0.f;
    float sx = 0.f, sy = 0.f, sz = 0.f;

    #pragma unroll
    for (int i = 0; i < 4; ++i) {
      const int p = oct * 4 + i;
      const float msk = (p < cnt) ? 1.f : 0.f;
      sx += q[i].x; sy += q[i].y; sz += q[i].z;
      const float ux = q[i].x * msk, uy = q[i].y * msk;
      const float uz = q[i].z * msk, uw = q[i].w * msk;
      tx += ux; ty += uy; tz += uz; tw += uw;
      p2a[0] += ux*ux; p2a[1] += ux*uy; p2a[2] += ux*uz; p2a[3] += ux*uw;
      p2a[4] += uy*uy; p2a[5] += uy*uz; p2a[6] += uy*uw;
      p2a[7] += uz*uz; p2a[8] += uz*uw;
      p2a[9] += uw*uw;
    }

    // combine the 7 linear sums across the octet (xor 1,2,4)
    #pragma unroll
    for (int m = 1; m <= 4; m <<= 1) {
      sx += __shfl_xor(sx, m, 64); sy += __shfl_xor(sy, m, 64);
      sz += __shfl_xor(sz, m, 64);
      tx += __shfl_xor(tx, m, 64); ty += __shfl_xor(ty, m, 64);
      tz += __shfl_xor(tz, m, 64); tw += __shfl_xor(tw, m, 64);
    }

    const float cf = (cnt > 0) ? (float)cnt : 1.f;
    const float rinv = 1.f / cf;
    float Kv[6];
    Kv[0] = sx * rinv; Kv[1] = sy * rinv; Kv[2] = sz * rinv;
    Kv[3] = (float)cd.w * VX_ + XOFF_;
    Kv[4] = (float)cd.z * VY_ + YOFF_;
    Kv[5] = (float)cd.y * VZ_ + ZOFF_;

    if (oct == 0) {   // packed record for k3
      unsigned nm01 = f2bfu(-Kv[0]) | (f2bfu(-Kv[1]) << 16);
      unsigned nm23 = f2bfu(-Kv[2]) | (f2bfu(-Kv[3]) << 16);
      unsigned nm45 = f2bfu(-Kv[4]) | (f2bfu(-Kv[5]) << 16);
      meanws[v] = make_int4((int)nm01, (int)nm23, (int)nm45, cnt);
    }

    // compact masked accumulation (all slot indices compile-time constant)
    const float T4[4] = {tx, ty, tz, tw};
    float cK[6];
    #pragma unroll
    for (int m = 0; m < 6; ++m) cK[m] = cf * Kv[m];

    #pragma unroll
    for (int r = 0; r < 4; ++r) {               // s = r
      mc[r >> 3] = fmaf(T4[r], fm[r & 7], mc[r >> 3]);
    }
    #pragma unroll
    for (int m = 0; m < 6; ++m) {               // s = 4 + m
      const int s = 4 + m;
      mc[s >> 3] = fmaf(cK[m], fm[s & 7], mc[s >> 3]);
    }
    #pragma unroll
    for (int m = 0; m < 6; ++m)                 // s = 10 + m*4 + r
      #pragma unroll
      for (int r = 0; r < 4; ++r) {
        const int s = 10 + m * 4 + r;
        mc[s >> 3] = fmaf(Kv[m] * T4[r], fm[s & 7], mc[s >> 3]);
      }
    {                                           // s = 34.. (upper-tri 6x6)
      int s = 34;
      #pragma unroll
      for (int m = 0; m < 6; ++m)
        #pragma unroll
        for (int m2 = m; m2 < 6; ++m2) {
          mc[s >> 3] = fmaf(cK[m] * Kv[m2], fm[s & 7], mc[s >> 3]);
          ++s;
        }
    }
  }

  // tail: compact regs sum the wave's 8 voxels (octet identity preserved)
  #pragma unroll
  for (int j = 0; j < 7; ++j) {
    float a = mc[j];
    a += __shfl_xor(a, 8, 64);
    a += __shfl_xor(a, 16, 64);
    a += __shfl_xor(a, 32, 64);
    mc[j] = a;
  }
  // P2: full 6-stage butterfly (sums octet AND voxels)
  #pragma unroll
  for (int i = 0; i < 10; ++i) {
    float a = p2a[i];
    #pragma unroll
    for (int m = 1; m <= 32; m <<= 1) a += __shfl_xor(a, m, 64);
    p2a[i] = a;
  }

  const int w = tid >> 6;
  const int lane = tid & 63;
  if (lane < 8) {
    #pragma unroll
    for (int j = 0; j < 7; ++j) {
      if (j < 6 || lane < 7)                 // s=55 belongs to P2
        red[w][8 * j + lane] = mc[j];
    }
  }
  if (lane == 0) {
    #pragma unroll
    for (int i = 0; i < 10; ++i) red[w][55 + i] = p2a[i];
  }
  __syncthreads();
  if (tid < NMOM) {
    const float val =
        (red[0][tid] + red[1][tid]) + (red[2][tid] + red[3][tid]);
    // HW fp32 atomic (no fence). ~98 adds per address across 16 sets.
    unsafeAtomicAdd(&acc[(blockIdx.x & (NSETS - 1)) * PSTRIDE + tid], val);
  }
}

// ---------------- Pass 2: 16 acc rows -> ab[128] (compact slot layout) ----
__global__ __launch_bounds__(256) void k2_finalize(
    const float* __restrict__ acc, const float* __restrict__ Wm,
    const float* __restrict__ gamma, const float* __restrict__ beta,
    float* __restrict__ ab)
{
  __shared__ double Sd[NMOM];
  const int t = threadIdx.x;

  if (t < NMOM) {
    double d = 0.0;
    #pragma unroll
    for (int r = 0; r < NSETS; ++r) d += (double)acc[r * PSTRIDE + t];
    Sd[t] = d;
  }
  __syncthreads();
  if (t < COUT) {
    const double N = (double)V_ * (double)P_;
    double w[NF];
    #pragma unroll
    for (int c = 0; c < NF; ++c) w[c] = (double)Wm[t * NF + c];
    const double W4[4] = {w[0] + w[4] + w[7], w[1] + w[5] + w[8],
                          w[2] + w[6] + w[9], w[3]};
    // mean*N = sum_r W4_r*ST_r - sum_m w_{4+m}*ScntK_m   (s0..9)
    double Sx = 0.0;
    #pragma unroll
    for (int r = 0; r < 4; ++r) Sx += W4[r] * Sd[r];
    #pragma unroll
    for (int m = 0; m < 6; ++m) Sx -= w[4 + m] * Sd[4 + m];
    const double mean = Sx / N;
    double ex2 = 0.0;
    {  // P2 quad form at s55..64 (upper-tri 4x4)
      int idx = 55;
      #pragma unroll
      for (int r = 0; r < 4; ++r)
        #pragma unroll
        for (int s = r; s < 4; ++s)
          ex2 += ((r == s) ? 1.0 : 2.0) * W4[r] * W4[s] * Sd[idx++];
    }
    {  // cross K*T at s10 + m*4 + r
      double cross = 0.0;
      #pragma unroll
      for (int m = 0; m < 6; ++m)
        #pragma unroll
        for (int r = 0; r < 4; ++r)
          cross += w[4 + m] * W4[r] * Sd[10 + m * 4 + r];
      ex2 -= 2.0 * cross;
    }
    {  // cntK*K at s34.. (upper-tri 6x6)
      int idx = 34;
      #pragma unroll
      for (int m = 0; m < 6; ++m)
        #pragma unroll
        for (int m2 = m; m2 < 6; ++m2)
          ex2 += ((m == m2) ? 1.0 : 2.0) * w[4 + m] * w[4 + m2] * Sd[idx++];
    }
    ex2 /= N;
    const double var = ex2 - mean * mean;
    const double rs = 1.0 / sqrt(var + (double)EPS_);
    const double a = (double)gamma[t] * rs;
    const double b = (double)beta[t] - mean * a;
    ab[t] = (float)a;
    ab[COUT + t] = (float)b;
  }
}

// ---------------- Pass 3: zero-LDS, zero-f64, masked pt loads -------------
__global__ __launch_bounds__(256) void k3_mfma(
    const float* __restrict__ vf, const float* __restrict__ Wm,
    const float* __restrict__ ab, const int4* __restrict__ meanws,
    float* __restrict__ out)
{
  const int tid  = threadIdx.x;
  const int lane = tid & 63;
  const int p    = lane & 31;
  const int half = lane >> 5;
  const int waveG = blockIdx.x * 4 + (tid >> 6);   // 0..12499

  // B fragments: B[k][n], n = lane&31, k = half*8+j.
  // k0..3: a*(W0+W4+W7, W1+W5+W8, W2+W6+W9, W3); k4..9: a*(W4..W9).
  const float a0 = ab[p],      b0 = ab[COUT + p];
  const float a1 = ab[32 + p], b1 = ab[COUT + 32 + p];
  short8 bf0, bf1;
  {
    const float* w0 = &Wm[p * NF];
    const float* w1 = &Wm[(32 + p) * NF];
    float t0[NF], t1[NF];
    t0[0] = a0 * (w0[0] + w0[4] + w0[7]);
    t0[1] = a0 * (w0[1] + w0[5] + w0[8]);
    t0[2] = a0 * (w0[2] + w0[6] + w0[9]);
    t0[3] = a0 * w0[3];
    t1[0] = a1 * (w1[0] + w1[4] + w1[7]);
    t1[1] = a1 * (w1[1] + w1[5] + w1[8]);
    t1[2] = a1 * (w1[2] + w1[6] + w1[9]);
    t1[3] = a1 * w1[3];
    #pragma unroll
    for (int k = 4; k < NF; ++k) { t0[k] = a0 * w0[k]; t1[k] = a1 * w1[k]; }

    uint4 bd0, bd1;
    unsigned p001 = f2bfu(t0[0]) | (f2bfu(t0[1]) << 16);
    unsigned p023 = f2bfu(t0[2]) | (f2bfu(t0[3]) << 16);
    unsigned p045 = f2bfu(t0[4]) | (f2bfu(t0[5]) << 16);
    unsigned p067 = f2bfu(t0[6]) | (f2bfu(t0[7]) << 16);
    unsigned p089 = f2bfu(t0[8]) | (f2bfu(t0[9]) << 16);
    unsigned p101 = f2bfu(t1[0]) | (f2bfu(t1[1]) << 16);
    unsigned p123 = f2bfu(t1[2]) | (f2bfu(t1[3]) << 16);
    unsigned p145 = f2bfu(t1[4]) | (f2bfu(t1[5]) << 16);
    unsigned p167 = f2bfu(t1[6]) | (f2bfu(t1[7]) << 16);
    unsigned p189 = f2bfu(t1[8]) | (f2bfu(t1[9]) << 16);
    bd0.x = half ? p089 : p001;  bd0.y = half ? 0u : p023;
    bd0.z = half ? 0u : p045;    bd0.w = half ? 0u : p067;
    bd1.x = half ? p189 : p101;  bd1.y = half ? 0u : p123;
    bd1.z = half ? 0u : p145;    bd1.w = half ? 0u : p167;
    bf0 = __builtin_bit_cast(short8, bd0);
    bf1 = __builtin_bit_cast(short8, bd1);
  }

  // ---- 2-deep pipeline; pt loads exec-masked to half==0 (only consumers) --
  float4 ptA = make_float4(0.f, 0.f, 0.f, 0.f), ptB = ptA;
  int vuA = __builtin_amdgcn_readfirstlane(waveG);
  int4 recA = meanws[vuA];
  if (half == 0) ptA = ((const float4*)vf)[vuA * P_ + p];
  int vuB = __builtin_amdgcn_readfirstlane(waveG + K3_WAVES);
  int4 recB = meanws[vuB];
  if (half == 0) ptB = ((const float4*)vf)[vuB * P_ + p];

  #pragma unroll
  for (int it = 0; it < K3_ITERS; ++it) {
    const int4   rec = recA;
    const float4 pt  = ptA;
    const int vcur = vuA;
    recA = recB; ptA = ptB; vuA = vuB;
    if (it + 2 < K3_ITERS) {
      vuB = __builtin_amdgcn_readfirstlane(waveG + (it + 2) * K3_WAVES);
      recB = meanws[vuB];
      if (half == 0) ptB = ((const float4*)vf)[vuB * P_ + p];
    }

    const int cnt = rec.w;
    const bool pm = p < cnt;
    unsigned dx = f2bfu(pm ? pt.x : 0.f) | (f2bfu(pm ? pt.y : 0.f) << 16);
    unsigned dy = f2bfu(pm ? pt.z : 0.f) | (f2bfu(pm ? pt.w : 0.f) << 16);
    unsigned m01 = pm ? (unsigned)rec.x : 0u;
    unsigned m23 = pm ? (unsigned)rec.y : 0u;
    unsigned m45 = pm ? (unsigned)rec.z : 0u;
    uint4 adw;
    adw.x = half ? m45 : dx;
    adw.y = half ? 0u  : dy;
    adw.z = half ? 0u  : m01;
    adw.w = half ? 0u  : m23;
    short8 af = __builtin_bit_cast(short8, adw);

    floatx16 c0 = {}, c1 = {};
    c0 = __builtin_amdgcn_mfma_f32_32x32x16_bf16(af, bf0, c0, 0, 0, 0);
    c1 = __builtin_amdgcn_mfma_f32_32x32x16_bf16(af, bf1, c1, 0, 0, 0);

    // max3 tree over the 16 accumulator rows (depth 3 vs 15-deep chain)
    float m0 = fmaxf(
        max3f(max3f(c0[0], c0[1], c0[2]), max3f(c0[3], c0[4], c0[5]),
              max3f(c0[6], c0[7], c0[8])),
        max3f(max3f(c0[9], c0[10], c0[11]), max3f(c0[12], c0[13], c0[14]),
              c0[15]));
    float m1 = fmaxf(
        max3f(max3f(c1[0], c1[1], c1[2]), max3f(c1[3], c1[4], c1[5]),
              max3f(c1[6], c1[7], c1[8])),
        max3f(max3f(c1[9], c1[10], c1[11]), max3f(c1[12], c1[13], c1[14]),
              c1[15]));
    m0 = fmaxf(m0, __shfl_xor(m0, 32, 64));
    m1 = fmaxf(m1, __shfl_xor(m1, 32, 64));
    float y = half ? fmaxf(b1 + m1, 0.f) : fmaxf(b0 + m0, 0.f);
    out[vcur * COUT + lane] = y;
  }
}

extern "C" void kernel_launch(void* const* d_in, const int* in_sizes, int n_in,
                              void* d_out, int out_size, void* d_ws, size_t ws_size,
                              hipStream_t stream)
{
  const float* vf     = (const float*)d_in[0];
  const int*   npts   = (const int*)d_in[1];
  const int*   coords = (const int*)d_in[2];
  const float* Wm     = (const float*)d_in[3];
  const float* gamma  = (const float*)d_in[4];
  const float* beta   = (const float*)d_in[5];
  float* out = (float*)d_out;

  float* ws = (float*)d_ws;
  float* acc    = ws;                            // 16*72 floats (atomic sets)
  float* ab     = ws + NSETS * PSTRIDE;          // 128 floats
  int4*  meanws = (int4*)(ws + NSETS * PSTRIDE + 128);  // V_ int4, 16B-aligned

  hipMemsetAsync(acc, 0, NSETS * PSTRIDE * sizeof(float), stream);
  k1_stats<<<K1_BLOCKS, 256, 0, stream>>>(vf, npts, coords, acc, meanws);
  k2_finalize<<<1, 256, 0, stream>>>(acc, Wm, gamma, beta, ab);
  k3_mfma<<<K3_BLOCKS, 256, 0, stream>>>(vf, Wm, ab, meanws, out);
}

// Round 8
// 123.987 us; speedup vs baseline: 1.0115x; 1.0115x over previous
//
#include <hip/hip_runtime.h>

// PillarVFE fused, 3 kernels + tiny memset.  FINAL (R17 state, best: 124.1us)
//  - R7/R8: no cross-block handoff inside a kernel (fence cost).
//  - R12: raw-moment-piece accumulation; R14: pipelining NEUTRAL (compiler
//    already pipelines); R15: dedicated 1-block k2, zero-LDS k3 (130.0).
//  - R16: k3 grid-stride + k1 fat-tail REGRESSED (+6).
//  - R17 (best, 124.1): k1 compact-slot accumulation (55 replicated entries
//    distributed over octet lanes, masked-fma; tail 225 -> 101 shuffles;
//    acc VGPRs 65 -> 17; 1563 blocks x 2 tiles, 6252 co-resident waves).
//  - R18: k3 pt loads masked to half==0 NEUTRAL/slightly neg => k3's vf reads
//    are L3-resident; k3 is latency/issue-bound, not BW-bound. Reverted.
//  Structural ledger at this point: ~84us fixed in-window harness fills +
//  k1 ~12-14 (BW floor 8.4) + k2+gaps+memset ~8 + k3 ~16-18 (L3-latency,
//  floor 12.4). Session ends on best verified state.
// k1: 8 thr/voxel (4 pts each), coalesced; 2 tiles/block; compact register
//     accumulators; butterfly + LDS reduce + 65 unsafeAtomicAdd at block end.
//     Writes per-voxel packed record (-mean,-center bf16, cnt).
//     Slot layout: s0..3 ST_r | s4..9 ScntK_m | s10..33 K_m*T_r |
//                  s34..54 cntK_m*K_m2 | s55..64 P2 upper-tri.
// k2: one block: sum 16 acc rows (double) -> per-channel a,b (f64 chain).
// k3: A=[xyzw,-mean,-ctr]*mask in MFMA K-slots, B=a*W'' bf16, C=0 -> D=a*x;
//     out = relu(b + max_rows D). One wave = one voxel/iter, 2-deep prefetch,
//     max3 tree.

typedef __attribute__((ext_vector_type(8))) short short8;     // 8 bf16
typedef __attribute__((ext_vector_type(16))) float floatx16;  // 32x32 MFMA C/D

namespace {
constexpr int V_    = 100000;
constexpr int P_    = 32;
constexpr int COUT  = 64;
constexpr int NF    = 10;
constexpr int NMOM  = 65;
constexpr int PSTRIDE = 72;
constexpr int NSETS  = 16;        // atomic accumulator rows
constexpr int NTILES = 3125;      // 32 voxels per tile
constexpr int K1_BLOCKS = 1563;   // x 2 tiles (last block: 1 tile)
constexpr int K1_TILES  = 2;
constexpr int K3_BLOCKS = 3125;   // 12500 waves x 8 iters = 100000 exactly
constexpr int K3_WAVES  = 12500;
constexpr int K3_ITERS  = 8;

constexpr float VX_ = 0.16f, VY_ = 0.16f, VZ_ = 4.0f;
constexpr float XOFF_ = 0.08f, YOFF_ = -39.60f, ZOFF_ = -1.0f;
constexpr float EPS_ = 0.001f;
}

__device__ __forceinline__ unsigned f2bfu(float x) {  // RNE -> 16-bit value
  unsigned u = __builtin_bit_cast(unsigned, x);
  u += 0x7fffu + ((u >> 16) & 1u);
  return u >> 16;
}

__device__ __forceinline__ float max3f(float a, float b, float c) {
  return fmaxf(fmaxf(a, b), c);   // fuses to v_max3_f32
}

// ---------------- Pass 1: compact raw-moment pieces ----------------
__global__ __launch_bounds__(256) void k1_stats(
    const float* __restrict__ vf, const int* __restrict__ npts,
    const int* __restrict__ coords, float* __restrict__ acc,
    int4* __restrict__ meanws)
{
  __shared__ float red[4][NMOM];

  const int tid = threadIdx.x;
  const int oct = tid & 7;          // 4-point slice within voxel
  const int vlane = tid >> 3;       // voxel-in-tile (0..31)

  // ownership masks: fm[k] = (oct==k) ? 1 : 0   (8 regs, static-indexed)
  float fm[8];
  #pragma unroll
  for (int k = 0; k < 8; ++k) fm[k] = (oct == k) ? 1.f : 0.f;

  float mc[7];                      // compact slots s = 8*j + oct, s<=54
  #pragma unroll
  for (int j = 0; j < 7; ++j) mc[j] = 0.f;
  float p2a[10];                    // per-lane P2 partials (additive)
  #pragma unroll
  for (int i = 0; i < 10; ++i) p2a[i] = 0.f;

  #pragma unroll
  for (int it = 0; it < K1_TILES; ++it) {
    const int tile = blockIdx.x * K1_TILES + it;   // 0..3125
    if (tile >= NTILES) break;                     // block-uniform guard
    const int v = tile * 32 + vlane;

    const int  cnt = npts[v];
    const int4 cd  = ((const int4*)coords)[v];

    // 4 float4 loads: 64B/thread -> wave covers 4KB contiguous
    float4 q[4];
    const float4* base = (const float4*)vf + (size_t)v * P_ + oct * 4;
    #pragma unroll
    for (int i = 0; i < 4; ++i) q[i] = base[i];

    float tx = 0.f, ty = 0.f, tz = 0.f, tw = 0.f;
    float sx = 0.f, sy = 0.f, sz = 0.f;

    #pragma unroll
    for (int i = 0; i < 4; ++i) {
      const int p = oct * 4 + i;
      const float msk = (p < cnt) ? 1.f : 0.f;
      sx += q[i].x; sy += q[i].y; sz += q[i].z;
      const float ux = q[i].x * msk, uy = q[i].y * msk;
      const float uz = q[i].z * msk, uw = q[i].w * msk;
      tx += ux; ty += uy; tz += uz; tw += uw;
      p2a[0] += ux*ux; p2a[1] += ux*uy; p2a[2] += ux*uz; p2a[3] += ux*uw;
      p2a[4] += uy*uy; p2a[5] += uy*uz; p2a[6] += uy*uw;
      p2a[7] += uz*uz; p2a[8] += uz*uw;
      p2a[9] += uw*uw;
    }

    // combine the 7 linear sums across the octet (xor 1,2,4)
    #pragma unroll
    for (int m = 1; m <= 4; m <<= 1) {
      sx += __shfl_xor(sx, m, 64); sy += __shfl_xor(sy, m, 64);
      sz += __shfl_xor(sz, m, 64);
      tx += __shfl_xor(tx, m, 64); ty += __shfl_xor(ty, m, 64);
      tz += __shfl_xor(tz, m, 64); tw += __shfl_xor(tw, m, 64);
    }

    const float cf = (cnt > 0) ? (float)cnt : 1.f;
    const float rinv = 1.f / cf;
    float Kv[6];
    Kv[0] = sx * rinv; Kv[1] = sy * rinv; Kv[2] = sz * rinv;
    Kv[3] = (float)cd.w * VX_ + XOFF_;
    Kv[4] = (float)cd.z * VY_ + YOFF_;
    Kv[5] = (float)cd.y * VZ_ + ZOFF_;

    if (oct == 0) {   // packed record for k3
      unsigned nm01 = f2bfu(-Kv[0]) | (f2bfu(-Kv[1]) << 16);
      unsigned nm23 = f2bfu(-Kv[2]) | (f2bfu(-Kv[3]) << 16);
      unsigned nm45 = f2bfu(-Kv[4]) | (f2bfu(-Kv[5]) << 16);
      meanws[v] = make_int4((int)nm01, (int)nm23, (int)nm45, cnt);
    }

    // compact masked accumulation (all slot indices compile-time constant)
    const float T4[4] = {tx, ty, tz, tw};
    float cK[6];
    #pragma unroll
    for (int m = 0; m < 6; ++m) cK[m] = cf * Kv[m];

    #pragma unroll
    for (int r = 0; r < 4; ++r) {               // s = r
      mc[r >> 3] = fmaf(T4[r], fm[r & 7], mc[r >> 3]);
    }
    #pragma unroll
    for (int m = 0; m < 6; ++m) {               // s = 4 + m
      const int s = 4 + m;
      mc[s >> 3] = fmaf(cK[m], fm[s & 7], mc[s >> 3]);
    }
    #pragma unroll
    for (int m = 0; m < 6; ++m)                 // s = 10 + m*4 + r
      #pragma unroll
      for (int r = 0; r < 4; ++r) {
        const int s = 10 + m * 4 + r;
        mc[s >> 3] = fmaf(Kv[m] * T4[r], fm[s & 7], mc[s >> 3]);
      }
    {                                           // s = 34.. (upper-tri 6x6)
      int s = 34;
      #pragma unroll
      for (int m = 0; m < 6; ++m)
        #pragma unroll
        for (int m2 = m; m2 < 6; ++m2) {
          mc[s >> 3] = fmaf(cK[m] * Kv[m2], fm[s & 7], mc[s >> 3]);
          ++s;
        }
    }
  }

  // tail: compact regs sum the wave's 8 voxels (octet identity preserved)
  #pragma unroll
  for (int j = 0; j < 7; ++j) {
    float a = mc[j];
    a += __shfl_xor(a, 8, 64);
    a += __shfl_xor(a, 16, 64);
    a += __shfl_xor(a, 32, 64);
    mc[j] = a;
  }
  // P2: full 6-stage butterfly (sums octet AND voxels)
  #pragma unroll
  for (int i = 0; i < 10; ++i) {
    float a = p2a[i];
    #pragma unroll
    for (int m = 1; m <= 32; m <<= 1) a += __shfl_xor(a, m, 64);
    p2a[i] = a;
  }

  const int w = tid >> 6;
  const int lane = tid & 63;
  if (lane < 8) {
    #pragma unroll
    for (int j = 0; j < 7; ++j) {
      if (j < 6 || lane < 7)                 // s=55 belongs to P2
        red[w][8 * j + lane] = mc[j];
    }
  }
  if (lane == 0) {
    #pragma unroll
    for (int i = 0; i < 10; ++i) red[w][55 + i] = p2a[i];
  }
  __syncthreads();
  if (tid < NMOM) {
    const float val =
        (red[0][tid] + red[1][tid]) + (red[2][tid] + red[3][tid]);
    // HW fp32 atomic (no fence). ~98 adds per address across 16 sets.
    unsafeAtomicAdd(&acc[(blockIdx.x & (NSETS - 1)) * PSTRIDE + tid], val);
  }
}

// ---------------- Pass 2: 16 acc rows -> ab[128] (compact slot layout) ----
__global__ __launch_bounds__(256) void k2_finalize(
    const float* __restrict__ acc, const float* __restrict__ Wm,
    const float* __restrict__ gamma, const float* __restrict__ beta,
    float* __restrict__ ab)
{
  __shared__ double Sd[NMOM];
  const int t = threadIdx.x;

  if (t < NMOM) {
    double d = 0.0;
    #pragma unroll
    for (int r = 0; r < NSETS; ++r) d += (double)acc[r * PSTRIDE + t];
    Sd[t] = d;
  }
  __syncthreads();
  if (t < COUT) {
    const double N = (double)V_ * (double)P_;
    double w[NF];
    #pragma unroll
    for (int c = 0; c < NF; ++c) w[c] = (double)Wm[t * NF + c];
    const double W4[4] = {w[0] + w[4] + w[7], w[1] + w[5] + w[8],
                          w[2] + w[6] + w[9], w[3]};
    // mean*N = sum_r W4_r*ST_r - sum_m w_{4+m}*ScntK_m   (s0..9)
    double Sx = 0.0;
    #pragma unroll
    for (int r = 0; r < 4; ++r) Sx += W4[r] * Sd[r];
    #pragma unroll
    for (int m = 0; m < 6; ++m) Sx -= w[4 + m] * Sd[4 + m];
    const double mean = Sx / N;
    double ex2 = 0.0;
    {  // P2 quad form at s55..64 (upper-tri 4x4)
      int idx = 55;
      #pragma unroll
      for (int r = 0; r < 4; ++r)
        #pragma unroll
        for (int s = r; s < 4; ++s)
          ex2 += ((r == s) ? 1.0 : 2.0) * W4[r] * W4[s] * Sd[idx++];
    }
    {  // cross K*T at s10 + m*4 + r
      double cross = 0.0;
      #pragma unroll
      for (int m = 0; m < 6; ++m)
        #pragma unroll
        for (int r = 0; r < 4; ++r)
          cross += w[4 + m] * W4[r] * Sd[10 + m * 4 + r];
      ex2 -= 2.0 * cross;
    }
    {  // cntK*K at s34.. (upper-tri 6x6)
      int idx = 34;
      #pragma unroll
      for (int m = 0; m < 6; ++m)
        #pragma unroll
        for (int m2 = m; m2 < 6; ++m2)
          ex2 += ((m == m2) ? 1.0 : 2.0) * w[4 + m] * w[4 + m2] * Sd[idx++];
    }
    ex2 /= N;
    const double var = ex2 - mean * mean;
    const double rs = 1.0 / sqrt(var + (double)EPS_);
    const double a = (double)gamma[t] * rs;
    const double b = (double)beta[t] - mean * a;
    ab[t] = (float)a;
    ab[COUT + t] = (float)b;
  }
}

// ---------------- Pass 3: zero-LDS, zero-f64 ----------------
__global__ __launch_bounds__(256) void k3_mfma(
    const float* __restrict__ vf, const float* __restrict__ Wm,
    const float* __restrict__ ab, const int4* __restrict__ meanws,
    float* __restrict__ out)
{
  const int tid  = threadIdx.x;
  const int lane = tid & 63;
  const int p    = lane & 31;
  const int half = lane >> 5;
  const int waveG = blockIdx.x * 4 + (tid >> 6);   // 0..12499

  // B fragments: B[k][n], n = lane&31, k = half*8+j.
  // k0..3: a*(W0+W4+W7, W1+W5+W8, W2+W6+W9, W3); k4..9: a*(W4..W9).
  const float a0 = ab[p],      b0 = ab[COUT + p];
  const float a1 = ab[32 + p], b1 = ab[COUT + 32 + p];
  short8 bf0, bf1;
  {
    const float* w0 = &Wm[p * NF];
    const float* w1 = &Wm[(32 + p) * NF];
    float t0[NF], t1[NF];
    t0[0] = a0 * (w0[0] + w0[4] + w0[7]);
    t0[1] = a0 * (w0[1] + w0[5] + w0[8]);
    t0[2] = a0 * (w0[2] + w0[6] + w0[9]);
    t0[3] = a0 * w0[3];
    t1[0] = a1 * (w1[0] + w1[4] + w1[7]);
    t1[1] = a1 * (w1[1] + w1[5] + w1[8]);
    t1[2] = a1 * (w1[2] + w1[6] + w1[9]);
    t1[3] = a1 * w1[3];
    #pragma unroll
    for (int k = 4; k < NF; ++k) { t0[k] = a0 * w0[k]; t1[k] = a1 * w1[k]; }

    uint4 bd0, bd1;
    unsigned p001 = f2bfu(t0[0]) | (f2bfu(t0[1]) << 16);
    unsigned p023 = f2bfu(t0[2]) | (f2bfu(t0[3]) << 16);
    unsigned p045 = f2bfu(t0[4]) | (f2bfu(t0[5]) << 16);
    unsigned p067 = f2bfu(t0[6]) | (f2bfu(t0[7]) << 16);
    unsigned p089 = f2bfu(t0[8]) | (f2bfu(t0[9]) << 16);
    unsigned p101 = f2bfu(t1[0]) | (f2bfu(t1[1]) << 16);
    unsigned p123 = f2bfu(t1[2]) | (f2bfu(t1[3]) << 16);
    unsigned p145 = f2bfu(t1[4]) | (f2bfu(t1[5]) << 16);
    unsigned p167 = f2bfu(t1[6]) | (f2bfu(t1[7]) << 16);
    unsigned p189 = f2bfu(t1[8]) | (f2bfu(t1[9]) << 16);
    bd0.x = half ? p089 : p001;  bd0.y = half ? 0u : p023;
    bd0.z = half ? 0u : p045;    bd0.w = half ? 0u : p067;
    bd1.x = half ? p189 : p101;  bd1.y = half ? 0u : p123;
    bd1.z = half ? 0u : p145;    bd1.w = half ? 0u : p167;
    bf0 = __builtin_bit_cast(short8, bd0);
    bf1 = __builtin_bit_cast(short8, bd1);
  }

  // ---- 2-deep pipeline: loads for it+2 in flight while computing it ----
  int vuA = __builtin_amdgcn_readfirstlane(waveG);
  int4   recA = meanws[vuA];
  float4 ptA  = ((const float4*)vf)[vuA * P_ + p];
  int vuB = __builtin_amdgcn_readfirstlane(waveG + K3_WAVES);
  int4   recB = meanws[vuB];
  float4 ptB  = ((const float4*)vf)[vuB * P_ + p];

  #pragma unroll
  for (int it = 0; it < K3_ITERS; ++it) {
    const int4   rec = recA;
    const float4 pt  = ptA;
    const int vcur = vuA;
    recA = recB; ptA = ptB; vuA = vuB;
    if (it + 2 < K3_ITERS) {
      vuB = __builtin_amdgcn_readfirstlane(waveG + (it + 2) * K3_WAVES);
      recB = meanws[vuB];
      ptB  = ((const float4*)vf)[vuB * P_ + p];
    }

    const int cnt = rec.w;
    const bool pm = p < cnt;
    unsigned dx = f2bfu(pm ? pt.x : 0.f) | (f2bfu(pm ? pt.y : 0.f) << 16);
    unsigned dy = f2bfu(pm ? pt.z : 0.f) | (f2bfu(pm ? pt.w : 0.f) << 16);
    unsigned m01 = pm ? (unsigned)rec.x : 0u;
    unsigned m23 = pm ? (unsigned)rec.y : 0u;
    unsigned m45 = pm ? (unsigned)rec.z : 0u;
    uint4 adw;
    adw.x = half ? m45 : dx;
    adw.y = half ? 0u  : dy;
    adw.z = half ? 0u  : m01;
    adw.w = half ? 0u  : m23;
    short8 af = __builtin_bit_cast(short8, adw);

    floatx16 c0 = {}, c1 = {};
    c0 = __builtin_amdgcn_mfma_f32_32x32x16_bf16(af, bf0, c0, 0, 0, 0);
    c1 = __builtin_amdgcn_mfma_f32_32x32x16_bf16(af, bf1, c1, 0, 0, 0);

    // max3 tree over the 16 accumulator rows (depth 3 vs 15-deep chain)
    float m0 = fmaxf(
        max3f(max3f(c0[0], c0[1], c0[2]), max3f(c0[3], c0[4], c0[5]),
              max3f(c0[6], c0[7], c0[8])),
        max3f(max3f(c0[9], c0[10], c0[11]), max3f(c0[12], c0[13], c0[14]),
              c0[15]));
    float m1 = fmaxf(
        max3f(max3f(c1[0], c1[1], c1[2]), max3f(c1[3], c1[4], c1[5]),
              max3f(c1[6], c1[7], c1[8])),
        max3f(max3f(c1[9], c1[10], c1[11]), max3f(c1[12], c1[13], c1[14]),
              c1[15]));
    m0 = fmaxf(m0, __shfl_xor(m0, 32, 64));
    m1 = fmaxf(m1, __shfl_xor(m1, 32, 64));
    float y = half ? fmaxf(b1 + m1, 0.f) : fmaxf(b0 + m0, 0.f);
    out[vcur * COUT + lane] = y;
  }
}

extern "C" void kernel_launch(void* const* d_in, const int* in_sizes, int n_in,
                              void* d_out, int out_size, void* d_ws, size_t ws_size,
                              hipStream_t stream)
{
  const float* vf     = (const float*)d_in[0];
  const int*   npts   = (const int*)d_in[1];
  const int*   coords = (const int*)d_in[2];
  const float* Wm     = (const float*)d_in[3];
  const float* gamma  = (const float*)d_in[4];
  const float* beta   = (const float*)d_in[5];
  float* out = (float*)d_out;

  float* ws = (float*)d_ws;
  float* acc    = ws;                            // 16*72 floats (atomic sets)
  float* ab     = ws + NSETS * PSTRIDE;          // 128 floats
  int4*  meanws = (int4*)(ws + NSETS * PSTRIDE + 128);  // V_ int4, 16B-aligned

  hipMemsetAsync(acc, 0, NSETS * PSTRIDE * sizeof(float), stream);
  k1_stats<<<K1_BLOCKS, 256, 0, stream>>>(vf, npts, coords, acc, meanws);
  k2_finalize<<<1, 256, 0, stream>>>(acc, Wm, gamma, beta, ab);
  k3_mfma<<<K3_BLOCKS, 256, 0, stream>>>(vf, Wm, ab, meanws, out);
}